// Round 20
// baseline (1454.735 us; speedup 1.0000x reference)
//
#include <hip/hip_runtime.h>
#include <hip/hip_bf16.h>
#include <math.h>

// ---- problem constants ----
#define BATCH   8
#define C_IN    3
#define IMG_SZ  224
#define P_SZ    16
#define NPATCH  196                 // (224/16)^2
#define MSEQ    197                 // NPATCH + cls
#define DDIM    192
#define EDIM    384
#define NSTATE  16
#define ENDIM   (EDIM*NSTATE)       // 6144
#define LLAYERS 2
#define ROWS    (BATCH*MSEQ)        // 1576
#define PROWS   (BATCH*NPATCH)      // 1568
#define PATCH_K (C_IN*P_SZ*P_SZ)    // 768
#define AP_ROWS 1664                // 13*128, padded M for MFMA tiles
#define MFRAGS  52                  // AP_ROWS/32
#define NFRAGS  192                 // ENDIM/32
#define KBLKS   24                  // EDIM/16
#define FRAG    512                 // u16 per fragment (64 lanes x 8)

typedef unsigned short u16;
typedef __attribute__((ext_vector_type(8))) short bf16x8;
typedef __attribute__((ext_vector_type(16))) float f32x16;

// precise silu (enters the scan only linearly)
__device__ __forceinline__ float silu_f(float x) { return x / (1.f + expf(-x)); }

// RNE fp32 -> bf16 (bit-level)
__device__ __forceinline__ u16 f2bf(float f) {
    unsigned u = __float_as_uint(f);
    unsigned r = (u + 0x7FFFu + ((u >> 16) & 1u)) >> 16;
    return (u16)r;
}
__device__ __forceinline__ float bf2f(u16 h) {
    return __uint_as_float(((unsigned)h) << 16);
}

// ------------------------------------------------------------------
// patchify: img (B,3,224,224) -> patches (PROWS, 768)
// ------------------------------------------------------------------
__global__ __launch_bounds__(256) void patchify_k(const float* __restrict__ img,
                                                  float* __restrict__ out) {
    int idx = blockIdx.x * 256 + threadIdx.x;
    if (idx >= PROWS * PATCH_K) return;
    int r = idx / PATCH_K, col = idx - r * PATCH_K;
    int b = r / NPATCH, p = r - b * NPATCH;
    int ph = p / 14, pw = p - ph * 14;
    int c = col >> 8, rem = col & 255, py = rem >> 4, px = rem & 15;
    out[idx] = img[((b * C_IN + c) * IMG_SZ + ph * P_SZ + py) * IMG_SZ + pw * P_SZ + px];
}

// ------------------------------------------------------------------
// assemble x = concat(cls, xemb) + pos   -> (B, MSEQ, DDIM)
// ------------------------------------------------------------------
__global__ __launch_bounds__(256) void assemble_k(const float* __restrict__ xemb,
                                                  const float* __restrict__ cls,
                                                  const float* __restrict__ pos,
                                                  float* __restrict__ x) {
    int idx = blockIdx.x * 256 + threadIdx.x;
    if (idx >= ROWS * DDIM) return;
    int d = idx % DDIM;
    int bm = idx / DDIM;
    int m = bm % MSEQ, b = bm / MSEQ;
    float v;
    if (m == 0) v = cls[d];
    else        v = xemb[((b * NPATCH) + (m - 1)) * DDIM + d];
    x[idx] = v + pos[m * DDIM + d];
}

// ------------------------------------------------------------------
// layernorm over last dim (DDIM=192), one wave per row
// ------------------------------------------------------------------
__global__ __launch_bounds__(256) void layernorm_k(const float* __restrict__ x,
                                                   const float* __restrict__ g,
                                                   const float* __restrict__ b,
                                                   float* __restrict__ o, int nrows) {
    int wave = threadIdx.x >> 6;
    int lane = threadIdx.x & 63;
    int row = blockIdx.x * 4 + wave;
    if (row >= nrows) return;
    const float* xr = x + (long)row * DDIM;
    float v0 = xr[lane], v1 = xr[lane + 64], v2 = xr[lane + 128];
    float s = v0 + v1 + v2;
    #pragma unroll
    for (int off = 1; off < 64; off <<= 1) s += __shfl_xor(s, off);
    float mu = s * (1.f / 192.f);
    float d0 = v0 - mu, d1 = v1 - mu, d2 = v2 - mu;
    float q = d0 * d0 + d1 * d1 + d2 * d2;
    #pragma unroll
    for (int off = 1; off < 64; off <<= 1) q += __shfl_xor(q, off);
    float inv = rsqrtf(q * (1.f / 192.f) + 1e-5f);
    float* orow = o + (long)row * DDIM;
    orow[lane]       = d0 * inv * g[lane]       + b[lane];
    orow[lane + 64]  = d1 * inv * g[lane + 64]  + b[lane + 64];
    orow[lane + 128] = d2 * inv * g[lane + 128] + b[lane + 128];
}

// ------------------------------------------------------------------
// convA: split xf/xb into 3 exact bf16 planes in MFMA FRAGMENT ORDER
// [3][MFRAGS][KBLKS][lane*8]: frag element j of lane l is
// A[row = mf*32 + (l&31)][k = kb*16 + (l>>5)*8 + j].
// A wave's frag read in the GEMM = 1KB contiguous. Pad rows -> 0.
// ------------------------------------------------------------------
__global__ __launch_bounds__(256) void convA_k(const float* __restrict__ xf,
                                               const float* __restrict__ xb,
                                               u16* __restrict__ Af3,
                                               u16* __restrict__ Ab3) {
    int idx = blockIdx.x * 256 + threadIdx.x;      // MFRAGS*KBLKS*64
    if (idx >= MFRAGS * KBLKS * 64) return;
    int lane = idx & 63;
    int kb = (idx >> 6) % KBLKS;
    int mf = idx / (64 * KBLKS);
    int row = mf * 32 + (lane & 31);
    int k = kb * 16 + (lane >> 5) * 8;
    long fo = ((long)mf * KBLKS + kb) * FRAG + (long)lane * 8;
    const long plane = (long)MFRAGS * KBLKS * FRAG;
    #pragma unroll
    for (int s = 0; s < 2; ++s) {
        const float* src = s ? xb : xf;
        u16* out = s ? Ab3 : Af3;
        uint4 hq = {0,0,0,0}, mq = {0,0,0,0}, lq = {0,0,0,0};
        if (row < ROWS) {
            u16* hp = (u16*)&hq; u16* mp = (u16*)&mq; u16* lp = (u16*)&lq;
            const float* xr = src + (long)row * EDIM + k;
            #pragma unroll
            for (int j = 0; j < 8; ++j) {
                float x = xr[j];
                u16 hb = f2bf(x);        float fh = bf2f(hb);
                float r1 = x - fh;
                u16 mb = f2bf(r1);       float fm = bf2f(mb);
                u16 lb = f2bf(r1 - fm);
                hp[j] = hb; mp[j] = mb; lp[j] = lb;
            }
        }
        *(uint4*)&out[fo] = hq;
        *(uint4*)&out[plane + fo] = mq;
        *(uint4*)&out[2 * plane + fo] = lq;
    }
}

// ------------------------------------------------------------------
// convWt: W (K=384 x N=6144 fp32) -> 3 bf16 planes in FRAGMENT ORDER
// [3][NFRAGS][KBLKS][lane*8]: element j of lane l is
// W[k = kb*16 + (l>>5)*8 + j][n = nf*32 + (l&31)].
// 64x64 LDS transpose; z in {0..3} selects {WBf,WCf,WBb,WCb}.
// ------------------------------------------------------------------
__global__ __launch_bounds__(256) void convWt_k(const float* __restrict__ W0,
                                                const float* __restrict__ W1,
                                                const float* __restrict__ W2,
                                                const float* __restrict__ W3,
                                                u16* __restrict__ Wt) {
    int z = blockIdx.z;
    const float* W = (z == 0) ? W0 : (z == 1) ? W1 : (z == 2) ? W2 : W3;
    const long plane = (long)NFRAGS * KBLKS * FRAG;
    u16* out = Wt + (long)z * 3L * plane;
    __shared__ float tile[64][65];
    int n0 = blockIdx.x * 64, k0 = blockIdx.y * 64;
    int t = threadIdx.x;
    #pragma unroll
    for (int i = 0; i < 16; ++i) {
        int id = t + 256 * i;
        int kk = id >> 6, nn = id & 63;
        tile[kk][nn] = W[(long)(k0 + kk) * ENDIM + n0 + nn];
    }
    __syncthreads();
    #pragma unroll
    for (int i = 0; i < 2; ++i) {
        int id = t + 256 * i;
        int nn = id >> 3, ch = id & 7;       // ch: k-chunk of 8 within the 64
        int n = n0 + nn;
        int kc = k0 + ch * 8;
        int nf = n >> 5, l31 = n & 31;
        int kb = kc >> 4, l5 = (kc >> 3) & 1;
        uint4 hq, mq, lq;
        u16* hp = (u16*)&hq; u16* mp = (u16*)&mq; u16* lp = (u16*)&lq;
        #pragma unroll
        for (int j = 0; j < 8; ++j) {
            float x = tile[ch * 8 + j][nn];
            u16 hb = f2bf(x);        float fh = bf2f(hb);
            float r1 = x - fh;
            u16 mb = f2bf(r1);       float fm = bf2f(mb);
            u16 lb = f2bf(r1 - fm);
            hp[j] = hb; mp[j] = mb; lp[j] = lb;
        }
        long fo = ((long)nf * KBLKS + kb) * FRAG + (long)(l5 * 32 + l31) * 8;
        *(uint4*)&out[fo] = hq;
        *(uint4*)&out[plane + fo] = mq;
        *(uint4*)&out[2 * plane + fo] = lq;
    }
}

// ------------------------------------------------------------------
// MFMA GEMM, 6-term bf16x3-split, fragment-ordered operands, LDS
// frag sharing (r19, proven +8%) with r20's 2-KB-PER-STAGE: stage
// TWO kb worth of frags (48KB LDS) per barrier pair -> barriers/block
// halve (48->24) and each in-flight gload hides under a DOUBLE MFMA
// cluster (384 issue-cyc/wave). Sub-kb processed in ascending order,
// same 6-term sequence: bit-identical results.
// C/D layout col=lane&31,row=(reg&3)+8*(reg>>2)+4*(lane>>5).
// gridDim.z=2 shares A across the {B,C} pair.
// ------------------------------------------------------------------
__global__ __launch_bounds__(256) void gemm_mfma(
        const u16* __restrict__ A3,                      // [3][MFRAGS][KBLKS][FRAG]
        const u16* __restrict__ Wt0, const float* __restrict__ b0, float* __restrict__ C0,
        const u16* __restrict__ Wt1, const float* __restrict__ b1, float* __restrict__ C1) {
    const u16* Wt     = blockIdx.z ? Wt1 : Wt0;          // [3][NFRAGS][KBLKS][FRAG]
    const float* bias = blockIdx.z ? b1 : b0;
    float* C          = blockIdx.z ? C1 : C0;
    __shared__ u16 lsb[2][24 * FRAG];                    // 48KB: per sub-kb, 12 A + 12 W
    int t = threadIdx.x;
    int lane = t & 63, wv = t >> 6;
    int wr = wv >> 1, wc = wv & 1;
    int l31 = lane & 31, l5 = lane >> 5;
    int mf0 = blockIdx.y * 4;
    int nf0 = blockIdx.x * 4;
    f32x16 acc[2][2] = {};

    // per-wave staging: wave wv owns frag slots 6*wv .. 6*wv+5 (per sub)
    long srcBase[6];
    {
        #pragma unroll
        for (int i = 0; i < 6; ++i) {
            int f = wv * 6 + i;
            if (f < 12)
                srcBase[i] = (((long)(f >> 2) * MFRAGS + mf0 + (f & 3)) * KBLKS) * FRAG + (long)lane * 8;
            else {
                int g = f - 12;
                srcBase[i] = (((long)(g >> 2) * NFRAGS + nf0 + (g & 3)) * KBLKS) * FRAG + (long)lane * 8;
            }
        }
    }
    const u16* gsrc = (wv < 2) ? A3 : Wt;
    u16* ldst0 = &lsb[0][(wv * 6) * FRAG + lane * 8];
    u16* ldst1 = &lsb[1][(wv * 6) * FRAG + lane * 8];

    uint4 ra[6], rb[6];
    auto gload = [&](int kb) {                // kb (even): loads kb -> ra, kb+1 -> rb
        long o0 = (long)kb * FRAG, o1 = o0 + FRAG;
        #pragma unroll
        for (int i = 0; i < 6; ++i) ra[i] = *(const uint4*)(gsrc + srcBase[i] + o0);
        #pragma unroll
        for (int i = 0; i < 6; ++i) rb[i] = *(const uint4*)(gsrc + srcBase[i] + o1);
    };
    auto swrite = [&]() {
        #pragma unroll
        for (int i = 0; i < 6; ++i) *(uint4*)(ldst0 + i * FRAG) = ra[i];
        #pragma unroll
        for (int i = 0; i < 6; ++i) *(uint4*)(ldst1 + i * FRAG) = rb[i];
    };

    gload(0);
    for (int kbp = 0; kbp < KBLKS / 2; ++kbp) {
        swrite();                             // vmcnt drains here (dep on ra/rb)
        __syncthreads();
        if (kbp + 1 < KBLKS / 2) gload(2 * (kbp + 1));   // in flight over 2 MFMA clusters
        #pragma unroll
        for (int sub = 0; sub < 2; ++sub) {   // ascending kb order -> bit-exact
            bf16x8 af[2][3], wf[2][3];
            #pragma unroll
            for (int r = 0; r < 2; ++r)
                #pragma unroll
                for (int p = 0; p < 3; ++p)
                    af[r][p] = *(const bf16x8*)&lsb[sub][(p * 4 + wr * 2 + r) * FRAG + lane * 8];
            #pragma unroll
            for (int c = 0; c < 2; ++c)
                #pragma unroll
                for (int p = 0; p < 3; ++p)
                    wf[c][p] = *(const bf16x8*)&lsb[sub][(12 + p * 4 + wc * 2 + c) * FRAG + lane * 8];
            #pragma unroll
            for (int r = 0; r < 2; ++r)
                #pragma unroll
                for (int c = 0; c < 2; ++c) {
                    f32x16 d = acc[r][c];
                    d = __builtin_amdgcn_mfma_f32_32x32x16_bf16(af[r][0], wf[c][0], d, 0, 0, 0);
                    d = __builtin_amdgcn_mfma_f32_32x32x16_bf16(af[r][0], wf[c][1], d, 0, 0, 0);
                    d = __builtin_amdgcn_mfma_f32_32x32x16_bf16(af[r][1], wf[c][0], d, 0, 0, 0);
                    d = __builtin_amdgcn_mfma_f32_32x32x16_bf16(af[r][0], wf[c][2], d, 0, 0, 0);
                    d = __builtin_amdgcn_mfma_f32_32x32x16_bf16(af[r][2], wf[c][0], d, 0, 0, 0);
                    d = __builtin_amdgcn_mfma_f32_32x32x16_bf16(af[r][1], wf[c][1], d, 0, 0, 0);
                    acc[r][c] = d;
                }
        }
        __syncthreads();                      // reads done before next swrite
    }
    int rowBase = blockIdx.y * 128;
    long colBase = (long)blockIdx.x * 128;
    #pragma unroll
    for (int r = 0; r < 2; ++r) {
        int rb2 = rowBase + wr * 64 + r * 32 + 4 * l5;
        #pragma unroll
        for (int c = 0; c < 2; ++c) {
            long cb = colBase + wc * 64 + c * 32 + l31;
            float bv = bias[cb];
            #pragma unroll
            for (int i = 0; i < 16; ++i) {
                int rr = rb2 + (i & 3) + 8 * (i >> 2);
                if (rr < ROWS) C[(long)rr * ENDIM + cb] = acc[r][c][i] + bv;
            }
        }
    }
}

// ------------------------------------------------------------------
// SMALL fp32 GEMM: one WAVE per 32x32 tile, 4x4/thread, double-
// buffered LDS. gridDim.z selects two independent sets (Wx+Wz, Df+Db).
// SP = correctly-rounded softplus epilogue. k-ascending FMA order
// (Delta path must stay bit-exact: P-trajectory depends on it).
// ------------------------------------------------------------------
#define SBK 16
template<bool SP, bool HASB2, bool HASRES>
__global__ __launch_bounds__(64) void gemm_s(const float* __restrict__ A0,
                                             const float* __restrict__ W0,
                                             const float* __restrict__ b10,
                                             const float* __restrict__ b20,
                                             const float* __restrict__ r0,
                                             float* __restrict__ C0,
                                             const float* __restrict__ A1,
                                             const float* __restrict__ W1,
                                             const float* __restrict__ b11,
                                             const float* __restrict__ b21,
                                             const float* __restrict__ r1,
                                             float* __restrict__ C1,
                                             int M, int N, int K) {
    const float* A  = blockIdx.z ? A1  : A0;
    const float* W  = blockIdx.z ? W1  : W0;
    const float* bp = blockIdx.z ? b11 : b10;
    const float* b2 = blockIdx.z ? b21 : b20;
    const float* rp = blockIdx.z ? r1  : r0;
    float*       C  = blockIdx.z ? C1  : C0;
    __shared__ float As[2][SBK][36];
    __shared__ float Wsh[2][SBK][36];
    int t = threadIdx.x;            // 0..63
    int tx = t & 7, ty = t >> 3;
    int rowBase = blockIdx.y * 32;
    long colBase = (long)blockIdx.x * 32;
    int rA = t >> 2, kqA = (t & 3) << 2;
    int kW = t >> 3, nqW = (t & 7) << 2;
    float acc[4][4] = {};
    int r0i = rowBase + rA, r1i = r0i + 16;

    auto loadA = [&](int k0, float4& a0, float4& a1) {
        a0 = make_float4(0.f,0.f,0.f,0.f); a1 = a0;
        if (r0i < M) a0 = *(const float4*)&A[(long)r0i * K + k0 + kqA];
        if (r1i < M) a1 = *(const float4*)&A[(long)r1i * K + k0 + kqA];
    };
    auto stage = [&](int buf, float4 a0, float4 a1, float4 w0, float4 w1) {
        As[buf][kqA + 0][rA] = a0.x; As[buf][kqA + 1][rA] = a0.y;
        As[buf][kqA + 2][rA] = a0.z; As[buf][kqA + 3][rA] = a0.w;
        As[buf][kqA + 0][rA + 16] = a1.x; As[buf][kqA + 1][rA + 16] = a1.y;
        As[buf][kqA + 2][rA + 16] = a1.z; As[buf][kqA + 3][rA + 16] = a1.w;
        *(float4*)&Wsh[buf][kW][nqW]     = w0;
        *(float4*)&Wsh[buf][kW + 8][nqW] = w1;
    };
    auto compute = [&](int buf) {
        #pragma unroll
        for (int kk = 0; kk < SBK; ++kk) {
            float4 av = *(const float4*)&As[buf][kk][ty << 2];
            float4 wv = *(const float4*)&Wsh[buf][kk][tx << 2];
            float ar[4] = {av.x, av.y, av.z, av.w};
            float wr[4] = {wv.x, wv.y, wv.z, wv.w};
            #pragma unroll
            for (int i = 0; i < 4; ++i)
                #pragma unroll
                for (int j = 0; j < 4; ++j) acc[i][j] += ar[i] * wr[j];
        }
    };

    {
        float4 a0, a1;
        loadA(0, a0, a1);
        float4 w0 = *(const float4*)&W[(long)kW * N + colBase + nqW];
        float4 w1 = *(const float4*)&W[(long)(kW + 8) * N + colBase + nqW];
        stage(0, a0, a1, w0, w1);
    }
    __syncthreads();
    int cur = 0;
    int nt = K / SBK;
    for (int kt = 1; kt < nt; ++kt) {
        int k0 = kt * SBK;
        float4 a0, a1;
        loadA(k0, a0, a1);
        float4 w0 = *(const float4*)&W[(long)(k0 + kW) * N + colBase + nqW];
        float4 w1 = *(const float4*)&W[(long)(k0 + kW + 8) * N + colBase + nqW];
        compute(cur);
        stage(cur ^ 1, a0, a1, w0, w1);
        __syncthreads();
        cur ^= 1;
    }
    compute(cur);

    #pragma unroll
    for (int i = 0; i < 4; ++i) {
        int r = rowBase + (ty << 2) + i;
        if (r >= M) break;
        long cb = colBase + (tx << 2);
        float vv[4];
        #pragma unroll
        for (int j = 0; j < 4; ++j) {
            float v = acc[i][j] + bp[cb + j];
            if (HASB2) v += b2[cb + j];
            if (SP) {  // correctly-rounded fp32 softplus via fp64
                double vd = (double)v;
                v = (float)(log1p(exp(-fabs(vd))) + fmax(vd, 0.0));
            }
            if (HASRES) v += rp[(long)r * N + cb + j];
            vv[j] = v;
        }
        float4 o; o.x = vv[0]; o.y = vv[1]; o.z = vv[2]; o.w = vv[3];
        *(float4*)&C[(long)r * N + cb] = o;
    }
}

// ------------------------------------------------------------------
// fused depthwise conv (fwd + bwd) + SiLU
// ------------------------------------------------------------------
__global__ __launch_bounds__(256) void dwconv_k(const float* __restrict__ xp,
                                                const float* __restrict__ wf,
                                                const float* __restrict__ bf,
                                                const float* __restrict__ wb,
                                                const float* __restrict__ bb,
                                                float* __restrict__ xf,
                                                float* __restrict__ xb) {
    int idx = blockIdx.x * 256 + threadIdx.x;
    if (idx >= ROWS * EDIM) return;
    int e = idx % EDIM;
    int bm = idx / EDIM;
    int m = bm % MSEQ, b = bm / MSEQ;
    const float* base = xp + (long)b * MSEQ * EDIM + e;
    float xm1 = (m > 0)        ? base[(m - 1) * EDIM] : 0.f;
    float x0  =                  base[m * EDIM];
    float xp1 = (m < MSEQ - 1) ? base[(m + 1) * EDIM] : 0.f;
    float f = wf[e * 3 + 0] * xm1 + wf[e * 3 + 1] * x0 + wf[e * 3 + 2] * xp1 + bf[e];
    float r = wb[e * 3 + 0] * xp1 + wb[e * 3 + 1] * x0 + wb[e * 3 + 2] * xm1 + bb[e];
    xf[idx] = silu_f(f);
    xb[idx] = silu_f(r);
}

// ------------------------------------------------------------------
// SSM recurrence, PHASE-PARALLEL, bit-exact fp32 chains; CR fp64
// transcendentals. One block per (b,e). ycomb!=nullptr fuses combine.
// ------------------------------------------------------------------
__global__ __launch_bounds__(256) void ssm_scan_k(const float* __restrict__ Bm,
                                                  const float* __restrict__ Cm,
                                                  const float* __restrict__ Dlt,
                                                  const float* __restrict__ xs,
                                                  const float* __restrict__ Apar,
                                                  float* __restrict__ y,
                                                  const float* __restrict__ yother,
                                                  const float* __restrict__ zg,
                                                  float* __restrict__ ycomb) {
#pragma clang fp contract(off)
    __shared__ float lgP[MSEQ][17];
    __shared__ float trm[MSEQ][17];
    __shared__ signed char sgn[MSEQ][17];
    int be = blockIdx.x;
    int b = be / EDIM, e = be - b * EDIM;
    int t = threadIdx.x;
    int n0 = t & 15;
    float Ap = Apar[e * NSTATE + n0];
    const long dxBase = (long)b * MSEQ * EDIM + e;
    const long bcBase = (long)b * MSEQ * ENDIM + e * NSTATE;

    for (int idx = t; idx < MSEQ * NSTATE; idx += 256) {
        int m = idx >> 4;
        float delta = Dlt[dxBase + (long)m * EDIM];
        float A = delta * Ap;
        float sa = (A > 0.f) ? 1.f : ((A < 0.f) ? -1.f : 0.f);
        float absA = fmaxf(fabsf(A), 1e-6f);
        lgP[m][n0] = (float)log((double)absA);
        sgn[m][n0] = (signed char)sa;
    }
    __syncthreads();
    if (t < NSTATE) {
        float cl = 0.f, cs = 1.f;
        for (int m = 0; m < MSEQ; ++m) {
            float sa = (float)sgn[m][t];
            cs = cs * sa;
            cl = cl + lgP[m][t];
            lgP[m][t] = cl;
            sgn[m][t] = (signed char)cs;
        }
    }
    __syncthreads();
    for (int idx = t; idx < MSEQ * NSTATE; idx += 256) {
        int m = idx >> 4;
        float cl = lgP[m][n0];
        float cs = (float)sgn[m][n0];
        float ex = (float)exp((double)cl);
        float P = cs * ex;
        float tt = P + 1e-6f;
        float invP = 1.0f / tt;
        float delta = Dlt[dxBase + (long)m * EDIM];
        float xv = xs[dxBase + (long)m * EDIM];
        float Bv = Bm[bcBase + (long)m * ENDIM + n0];
        float Bfull = delta * Bv;
        float t1 = invP * Bfull;
        float t2 = t1 * xv;
        trm[m][n0] = t2;
        lgP[m][n0] = P;
    }
    __syncthreads();
    if (t < NSTATE) {
        float S = 0.f;
        for (int m = 0; m < MSEQ; ++m) {
            S = S + trm[m][t];
            float h = lgP[m][t] * S;
            trm[m][t] = h;
        }
    }
    __syncthreads();
    for (int m = t; m < MSEQ; m += 256) {
        const float* cp = &Cm[bcBase + (long)m * ENDIM];
        float a[16];
        #pragma unroll
        for (int n = 0; n < 16; ++n) a[n] = trm[m][n] * cp[n];
        float b0 = a[0] + a[8],  b1 = a[1] + a[9];
        float b2v = a[2] + a[10], b3 = a[3] + a[11];
        float b4 = a[4] + a[12], b5 = a[5] + a[13];
        float b6 = a[6] + a[14], b7 = a[7] + a[15];
        float c0 = b0 + b1, c2 = b2v + b3, c4 = b4 + b5, c6 = b6 + b7;
        float d0 = c0 + c2, d4 = c4 + c6;
        float val = d0 + d4;
        long o = dxBase + (long)m * EDIM;
        if (ycomb) ycomb[o] = (yother[o] + val) * silu_f(zg[o]);
        else       y[o] = val;
    }
}

extern "C" void kernel_launch(void* const* d_in, const int* in_sizes, int n_in,
                              void* d_out, int out_size, void* d_ws, size_t ws_size,
                              hipStream_t stream) {
    const float* img     = (const float*)d_in[0];
    const float* patch_w = (const float*)d_in[1];
    const float* patch_b = (const float*)d_in[2];
    const float* cls     = (const float*)d_in[3];
    const float* pos     = (const float*)d_in[4];
    const float* ln_g    = (const float*)d_in[5];
    const float* ln_b    = (const float*)d_in[6];
    const float* Wx  = (const float*)d_in[7];  const float* bx  = (const float*)d_in[8];
    const float* Wz  = (const float*)d_in[9];  const float* bz  = (const float*)d_in[10];
    const float* cwf = (const float*)d_in[11]; const float* cbf = (const float*)d_in[12];
    const float* cwb = (const float*)d_in[13]; const float* cbb = (const float*)d_in[14];
    const float* WBf = (const float*)d_in[15]; const float* bBf = (const float*)d_in[16];
    const float* WCf = (const float*)d_in[17]; const float* bCf = (const float*)d_in[18];
    const float* WDf = (const float*)d_in[19]; const float* bDf = (const float*)d_in[20];
    const float* Af  = (const float*)d_in[21]; const float* dbf = (const float*)d_in[22];
    const float* WBb = (const float*)d_in[23]; const float* bBb = (const float*)d_in[24];
    const float* WCb = (const float*)d_in[25]; const float* bCb = (const float*)d_in[26];
    const float* WDb = (const float*)d_in[27]; const float* bDb = (const float*)d_in[28];
    const float* Ab  = (const float*)d_in[29]; const float* dbb = (const float*)d_in[30];
    const float* Wout= (const float*)d_in[31]; const float* bout= (const float*)d_in[32];
    const float* ng  = (const float*)d_in[33]; const float* nb  = (const float*)d_in[34];

    float* ws = (float*)d_ws;
    float* xA   = ws;
    float* xB   = xA  + (size_t)ROWS * DDIM;
    float* xn   = xB  + (size_t)ROWS * DDIM;
    float* xp   = xn  + (size_t)ROWS * DDIM;
    float* zb   = xp  + (size_t)ROWS * EDIM;
    float* xfb  = zb  + (size_t)ROWS * EDIM;
    float* xbb  = xfb + (size_t)ROWS * EDIM;
    float* yfb  = xbb + (size_t)ROWS * EDIM;
    float* ybb  = yfb + (size_t)ROWS * EDIM;
    float* ycb  = ybb + (size_t)ROWS * EDIM;
    float* dlt  = ycb + (size_t)ROWS * EDIM;
    float* dlt2 = dlt + (size_t)ROWS * EDIM;
    float* Bmb  = dlt2 + (size_t)ROWS * EDIM;         // ROWS*ENDIM
    float* Cmb  = Bmb + (size_t)ROWS * ENDIM;
    u16*   Af3  = (u16*)(Cmb + (size_t)ROWS * ENDIM); // [3][MFRAGS][KBLKS][FRAG]
    u16*   Ab3  = Af3 + 3L * MFRAGS * KBLKS * FRAG;
    u16*   Wt4  = Ab3 + 3L * MFRAGS * KBLKS * FRAG;   // [4][3][NFRAGS][KBLKS][FRAG]
    // patchify scratch aliases the (not-yet-needed) B buffer
    float* patches = Bmb;                             // PROWS*PATCH_K
    float* xemb    = Bmb + (size_t)PROWS * PATCH_K;   // PROWS*DDIM

    const long WtSz = 3L * NFRAGS * KBLKS * FRAG;     // u16 per converted matrix

    // --- patch embedding ---
    patchify_k<<<(PROWS * PATCH_K + 255) / 256, 256, 0, stream>>>(img, patches);
    {   // 1568x192x768 GEMM
        dim3 g(DDIM / 32, (PROWS + 31) / 32, 1);
        gemm_s<false, false, false><<<g, 64, 0, stream>>>(
            patches, patch_w, patch_b, nullptr, nullptr, xemb,
            patches, patch_w, patch_b, nullptr, nullptr, xemb,
            PROWS, DDIM, PATCH_K);
    }
    assemble_k<<<(ROWS * DDIM + 255) / 256, 256, 0, stream>>>(xemb, cls, pos, xA);

    float* cur = xA; float* nxt = xB;
    for (int i = 0; i < LLAYERS; ++i) {
        layernorm_k<<<(ROWS + 3) / 4, 256, 0, stream>>>(cur, ln_g + i * DDIM, ln_b + i * DDIM, xn, ROWS);
        {   // Wx + Wz fused (shared A=xn)
            dim3 g(EDIM / 32, (ROWS + 31) / 32, 2);
            gemm_s<false, false, false><<<g, 64, 0, stream>>>(
                xn, Wx + (size_t)i * DDIM * EDIM, bx + i * EDIM, nullptr, nullptr, xp,
                xn, Wz + (size_t)i * DDIM * EDIM, bz + i * EDIM, nullptr, nullptr, zb,
                ROWS, EDIM, DDIM);
        }
        dwconv_k<<<(ROWS * EDIM + 255) / 256, 256, 0, stream>>>(xp, cwf + i * EDIM * 3, cbf + i * EDIM,
                                                                cwb + i * EDIM * 3, cbb + i * EDIM, xfb, xbb);
        convA_k<<<(MFRAGS * KBLKS * 64 + 255) / 256, 256, 0, stream>>>(xfb, xbb, Af3, Ab3);
        {   // Df + Db fused (CR softplus epilogue) — fp32 path, P stays bit-exact
            dim3 g(EDIM / 32, (ROWS + 31) / 32, 2);
            gemm_s<true, true, false><<<g, 64, 0, stream>>>(
                xfb, WDf + (size_t)i * EDIM * EDIM, bDf + i * EDIM, dbf + i * EDIM, nullptr, dlt,
                xbb, WDb + (size_t)i * EDIM * EDIM, bDb + i * EDIM, dbb + i * EDIM, nullptr, dlt2,
                ROWS, EDIM, EDIM);
        }
        {   // convert the 4 big weight matrices -> fragment-ordered bf16x3 planes
            dim3 g(ENDIM / 64, EDIM / 64, 4);
            convWt_k<<<g, 256, 0, stream>>>(
                WBf + (size_t)i * EDIM * ENDIM, WCf + (size_t)i * EDIM * ENDIM,
                WBb + (size_t)i * EDIM * ENDIM, WCb + (size_t)i * EDIM * ENDIM, Wt4);
        }
        {   // Bf + Cf via MFMA (shared A planes); 128x128 tiles
            dim3 g(ENDIM / 128, AP_ROWS / 128, 2);
            gemm_mfma<<<g, 256, 0, stream>>>(
                Af3,
                Wt4 + 0 * WtSz, bBf + i * ENDIM, Bmb,
                Wt4 + 1 * WtSz, bCf + i * ENDIM, Cmb);
        }
        ssm_scan_k<<<BATCH * EDIM, 256, 0, stream>>>(Bmb, Cmb, dlt, xfb, Af + i * EDIM * NSTATE,
                                                     yfb, nullptr, nullptr, nullptr);
        {   // Bb + Cb via MFMA
            dim3 g(ENDIM / 128, AP_ROWS / 128, 2);
            gemm_mfma<<<g, 256, 0, stream>>>(
                Ab3,
                Wt4 + 2 * WtSz, bBb + i * ENDIM, Bmb,
                Wt4 + 3 * WtSz, bCb + i * ENDIM, Cmb);
        }
        // bwd scan with FUSED combine: ycb = (yfb + y_b) * silu(zb)
        ssm_scan_k<<<BATCH * EDIM, 256, 0, stream>>>(Bmb, Cmb, dlt2, xbb, Ab + i * EDIM * NSTATE,
                                                     ybb, yfb, zb, ycb);
        {   // Wout with residual
            dim3 g(DDIM / 32, (ROWS + 31) / 32, 1);
            gemm_s<false, false, true><<<g, 64, 0, stream>>>(
                ycb, Wout + (size_t)i * EDIM * DDIM, bout + i * DDIM, nullptr, cur, nxt,
                ycb, Wout + (size_t)i * EDIM * DDIM, bout + i * DDIM, nullptr, cur, nxt,
                ROWS, DDIM, EDIM);
        }
        float* t = cur; cur = nxt; nxt = t;
    }
    layernorm_k<<<(ROWS + 3) / 4, 256, 0, stream>>>(cur, ng, nb, (float*)d_out, ROWS);
}

// Round 21
// 920.625 us; speedup vs baseline: 1.5802x; 1.5802x over previous
//
#include <hip/hip_runtime.h>
#include <hip/hip_bf16.h>
#include <math.h>

// ---- problem constants ----
#define BATCH   8
#define C_IN    3
#define IMG_SZ  224
#define P_SZ    16
#define NPATCH  196                 // (224/16)^2
#define MSEQ    197                 // NPATCH + cls
#define DDIM    192
#define EDIM    384
#define NSTATE  16
#define ENDIM   (EDIM*NSTATE)       // 6144
#define LLAYERS 2
#define ROWS    (BATCH*MSEQ)        // 1576
#define PROWS   (BATCH*NPATCH)      // 1568
#define PATCH_K (C_IN*P_SZ*P_SZ)    // 768
#define AP_ROWS 1664                // 13*128, padded M for MFMA tiles
#define MFRAGS  52                  // AP_ROWS/32
#define NFRAGS  192                 // ENDIM/32
#define KBLKS   24                  // EDIM/16
#define FRAG    512                 // u16 per fragment (64 lanes x 8)

typedef unsigned short u16;
typedef __attribute__((ext_vector_type(8))) short bf16x8;
typedef __attribute__((ext_vector_type(16))) float f32x16;

// precise silu (enters the scan only linearly)
__device__ __forceinline__ float silu_f(float x) { return x / (1.f + expf(-x)); }

// RNE fp32 -> bf16 (bit-level)
__device__ __forceinline__ u16 f2bf(float f) {
    unsigned u = __float_as_uint(f);
    unsigned r = (u + 0x7FFFu + ((u >> 16) & 1u)) >> 16;
    return (u16)r;
}
__device__ __forceinline__ float bf2f(u16 h) {
    return __uint_as_float(((unsigned)h) << 16);
}

// ------------------------------------------------------------------
// patchify: img (B,3,224,224) -> patches (PROWS, 768)
// ------------------------------------------------------------------
__global__ __launch_bounds__(256) void patchify_k(const float* __restrict__ img,
                                                  float* __restrict__ out) {
    int idx = blockIdx.x * 256 + threadIdx.x;
    if (idx >= PROWS * PATCH_K) return;
    int r = idx / PATCH_K, col = idx - r * PATCH_K;
    int b = r / NPATCH, p = r - b * NPATCH;
    int ph = p / 14, pw = p - ph * 14;
    int c = col >> 8, rem = col & 255, py = rem >> 4, px = rem & 15;
    out[idx] = img[((b * C_IN + c) * IMG_SZ + ph * P_SZ + py) * IMG_SZ + pw * P_SZ + px];
}

// ------------------------------------------------------------------
// assemble x = concat(cls, xemb) + pos   -> (B, MSEQ, DDIM)
// ------------------------------------------------------------------
__global__ __launch_bounds__(256) void assemble_k(const float* __restrict__ xemb,
                                                  const float* __restrict__ cls,
                                                  const float* __restrict__ pos,
                                                  float* __restrict__ x) {
    int idx = blockIdx.x * 256 + threadIdx.x;
    if (idx >= ROWS * DDIM) return;
    int d = idx % DDIM;
    int bm = idx / DDIM;
    int m = bm % MSEQ, b = bm / MSEQ;
    float v;
    if (m == 0) v = cls[d];
    else        v = xemb[((b * NPATCH) + (m - 1)) * DDIM + d];
    x[idx] = v + pos[m * DDIM + d];
}

// ------------------------------------------------------------------
// layernorm over last dim (DDIM=192), one wave per row
// ------------------------------------------------------------------
__global__ __launch_bounds__(256) void layernorm_k(const float* __restrict__ x,
                                                   const float* __restrict__ g,
                                                   const float* __restrict__ b,
                                                   float* __restrict__ o, int nrows) {
    int wave = threadIdx.x >> 6;
    int lane = threadIdx.x & 63;
    int row = blockIdx.x * 4 + wave;
    if (row >= nrows) return;
    const float* xr = x + (long)row * DDIM;
    float v0 = xr[lane], v1 = xr[lane + 64], v2 = xr[lane + 128];
    float s = v0 + v1 + v2;
    #pragma unroll
    for (int off = 1; off < 64; off <<= 1) s += __shfl_xor(s, off);
    float mu = s * (1.f / 192.f);
    float d0 = v0 - mu, d1 = v1 - mu, d2 = v2 - mu;
    float q = d0 * d0 + d1 * d1 + d2 * d2;
    #pragma unroll
    for (int off = 1; off < 64; off <<= 1) q += __shfl_xor(q, off);
    float inv = rsqrtf(q * (1.f / 192.f) + 1e-5f);
    float* orow = o + (long)row * DDIM;
    orow[lane]       = d0 * inv * g[lane]       + b[lane];
    orow[lane + 64]  = d1 * inv * g[lane + 64]  + b[lane + 64];
    orow[lane + 128] = d2 * inv * g[lane + 128] + b[lane + 128];
}

// ------------------------------------------------------------------
// convA: split xf/xb into 3 exact bf16 planes in MFMA FRAGMENT ORDER
// [3][MFRAGS][KBLKS][lane*8]: frag element j of lane l is
// A[row = mf*32 + (l&31)][k = kb*16 + (l>>5)*8 + j].
// A wave's frag read in the GEMM = 1KB contiguous. Pad rows -> 0.
// ------------------------------------------------------------------
__global__ __launch_bounds__(256) void convA_k(const float* __restrict__ xf,
                                               const float* __restrict__ xb,
                                               u16* __restrict__ Af3,
                                               u16* __restrict__ Ab3) {
    int idx = blockIdx.x * 256 + threadIdx.x;      // MFRAGS*KBLKS*64
    if (idx >= MFRAGS * KBLKS * 64) return;
    int lane = idx & 63;
    int kb = (idx >> 6) % KBLKS;
    int mf = idx / (64 * KBLKS);
    int row = mf * 32 + (lane & 31);
    int k = kb * 16 + (lane >> 5) * 8;
    long fo = ((long)mf * KBLKS + kb) * FRAG + (long)lane * 8;
    const long plane = (long)MFRAGS * KBLKS * FRAG;
    #pragma unroll
    for (int s = 0; s < 2; ++s) {
        const float* src = s ? xb : xf;
        u16* out = s ? Ab3 : Af3;
        uint4 hq = {0,0,0,0}, mq = {0,0,0,0}, lq = {0,0,0,0};
        if (row < ROWS) {
            u16* hp = (u16*)&hq; u16* mp = (u16*)&mq; u16* lp = (u16*)&lq;
            const float* xr = src + (long)row * EDIM + k;
            #pragma unroll
            for (int j = 0; j < 8; ++j) {
                float x = xr[j];
                u16 hb = f2bf(x);        float fh = bf2f(hb);
                float r1 = x - fh;
                u16 mb = f2bf(r1);       float fm = bf2f(mb);
                u16 lb = f2bf(r1 - fm);
                hp[j] = hb; mp[j] = mb; lp[j] = lb;
            }
        }
        *(uint4*)&out[fo] = hq;
        *(uint4*)&out[plane + fo] = mq;
        *(uint4*)&out[2 * plane + fo] = lq;
    }
}

// ------------------------------------------------------------------
// convWt: W (K=384 x N=6144 fp32) -> 3 bf16 planes in FRAGMENT ORDER
// [3][NFRAGS][KBLKS][lane*8]: element j of lane l is
// W[k = kb*16 + (l>>5)*8 + j][n = nf*32 + (l&31)].
// 64x64 LDS transpose; z in {0..3} selects {WBf,WCf,WBb,WCb}.
// ------------------------------------------------------------------
__global__ __launch_bounds__(256) void convWt_k(const float* __restrict__ W0,
                                                const float* __restrict__ W1,
                                                const float* __restrict__ W2,
                                                const float* __restrict__ W3,
                                                u16* __restrict__ Wt) {
    int z = blockIdx.z;
    const float* W = (z == 0) ? W0 : (z == 1) ? W1 : (z == 2) ? W2 : W3;
    const long plane = (long)NFRAGS * KBLKS * FRAG;
    u16* out = Wt + (long)z * 3L * plane;
    __shared__ float tile[64][65];
    int n0 = blockIdx.x * 64, k0 = blockIdx.y * 64;
    int t = threadIdx.x;
    #pragma unroll
    for (int i = 0; i < 16; ++i) {
        int id = t + 256 * i;
        int kk = id >> 6, nn = id & 63;
        tile[kk][nn] = W[(long)(k0 + kk) * ENDIM + n0 + nn];
    }
    __syncthreads();
    #pragma unroll
    for (int i = 0; i < 2; ++i) {
        int id = t + 256 * i;
        int nn = id >> 3, ch = id & 7;       // ch: k-chunk of 8 within the 64
        int n = n0 + nn;
        int kc = k0 + ch * 8;
        int nf = n >> 5, l31 = n & 31;
        int kb = kc >> 4, l5 = (kc >> 3) & 1;
        uint4 hq, mq, lq;
        u16* hp = (u16*)&hq; u16* mp = (u16*)&mq; u16* lp = (u16*)&lq;
        #pragma unroll
        for (int j = 0; j < 8; ++j) {
            float x = tile[ch * 8 + j][nn];
            u16 hb = f2bf(x);        float fh = bf2f(hb);
            float r1 = x - fh;
            u16 mb = f2bf(r1);       float fm = bf2f(mb);
            u16 lb = f2bf(r1 - fm);
            hp[j] = hb; mp[j] = mb; lp[j] = lb;
        }
        long fo = ((long)nf * KBLKS + kb) * FRAG + (long)(l5 * 32 + l31) * 8;
        *(uint4*)&out[fo] = hq;
        *(uint4*)&out[plane + fo] = mq;
        *(uint4*)&out[2 * plane + fo] = lq;
    }
}

// ------------------------------------------------------------------
// MFMA GEMM, 6-term bf16x3-split, fragment-ordered operands, with
// LDS FRAG SHARING — the r19 design point, empirically the optimum:
// every perturbation measured and negative (r15 bigger tile -50%,
// r16 reg-dbuf -16%, r17 setprio/NT -6%, r18 smaller tile -23%,
// r20 2-kb staging -137% via scratch spills). 24 unique frags
// (12 A + 12 W) staged once per block-kb into 24KB LDS; gload(kb+1)
// issues before the ds_read+MFMA cluster (latency hidden under
// ~775 cyc of MFMA); 2 barriers/kb; 84 VGPR + 64 AGPR, no spill.
// kb-ascending, same 6-term order per output: bit-identical results.
// C/D layout col=lane&31,row=(reg&3)+8*(reg>>2)+4*(lane>>5).
// gridDim.z=2 shares A across the {B,C} pair.
// ------------------------------------------------------------------
__global__ __launch_bounds__(256) void gemm_mfma(
        const u16* __restrict__ A3,                      // [3][MFRAGS][KBLKS][FRAG]
        const u16* __restrict__ Wt0, const float* __restrict__ b0, float* __restrict__ C0,
        const u16* __restrict__ Wt1, const float* __restrict__ b1, float* __restrict__ C1) {
    const u16* Wt     = blockIdx.z ? Wt1 : Wt0;          // [3][NFRAGS][KBLKS][FRAG]
    const float* bias = blockIdx.z ? b1 : b0;
    float* C          = blockIdx.z ? C1 : C0;
    __shared__ u16 lsb[24 * FRAG];                       // 24KB: slots 0-11 A, 12-23 W
    int t = threadIdx.x;
    int lane = t & 63, wv = t >> 6;
    int wr = wv >> 1, wc = wv & 1;
    int l31 = lane & 31, l5 = lane >> 5;
    int mf0 = blockIdx.y * 4;
    int nf0 = blockIdx.x * 4;
    f32x16 acc[2][2] = {};

    // per-wave staging: wave wv owns frag slots 6*wv .. 6*wv+5
    // slot f<12: A plane p=f>>2, mi=f&3 ; slot>=12: W plane g>>2, ni=g&3
    long srcBase[6];
    {
        #pragma unroll
        for (int i = 0; i < 6; ++i) {
            int f = wv * 6 + i;
            if (f < 12)
                srcBase[i] = (((long)(f >> 2) * MFRAGS + mf0 + (f & 3)) * KBLKS) * FRAG + (long)lane * 8;
            else {
                int g = f - 12;
                srcBase[i] = (((long)(g >> 2) * NFRAGS + nf0 + (g & 3)) * KBLKS) * FRAG + (long)lane * 8;
            }
        }
    }
    const u16* gsrc = (wv < 2) ? A3 : Wt;
    u16* ldst = &lsb[(wv * 6) * FRAG + lane * 8];

    uint4 r0, r1, r2, r3, r4, r5;
    auto gload = [&](int kb) {
        long o = (long)kb * FRAG;
        r0 = *(const uint4*)(gsrc + srcBase[0] + o);
        r1 = *(const uint4*)(gsrc + srcBase[1] + o);
        r2 = *(const uint4*)(gsrc + srcBase[2] + o);
        r3 = *(const uint4*)(gsrc + srcBase[3] + o);
        r4 = *(const uint4*)(gsrc + srcBase[4] + o);
        r5 = *(const uint4*)(gsrc + srcBase[5] + o);
    };
    auto swrite = [&]() {
        *(uint4*)(ldst + 0 * FRAG) = r0;
        *(uint4*)(ldst + 1 * FRAG) = r1;
        *(uint4*)(ldst + 2 * FRAG) = r2;
        *(uint4*)(ldst + 3 * FRAG) = r3;
        *(uint4*)(ldst + 4 * FRAG) = r4;
        *(uint4*)(ldst + 5 * FRAG) = r5;
    };

    gload(0);
    for (int kb = 0; kb < KBLKS; ++kb) {
        swrite();                         // vmcnt(0) auto-inserted (dep on r*)
        __syncthreads();                  // stage visible to all waves
        if (kb + 1 < KBLKS) gload(kb + 1);    // in flight during MFMA cluster
        bf16x8 af[2][3], wf[2][3];
        #pragma unroll
        for (int r = 0; r < 2; ++r)
            #pragma unroll
            for (int p = 0; p < 3; ++p)
                af[r][p] = *(const bf16x8*)&lsb[(p * 4 + wr * 2 + r) * FRAG + lane * 8];
        #pragma unroll
        for (int c = 0; c < 2; ++c)
            #pragma unroll
            for (int p = 0; p < 3; ++p)
                wf[c][p] = *(const bf16x8*)&lsb[(12 + p * 4 + wc * 2 + c) * FRAG + lane * 8];
        #pragma unroll
        for (int r = 0; r < 2; ++r)
            #pragma unroll
            for (int c = 0; c < 2; ++c) {
                f32x16 d = acc[r][c];
                d = __builtin_amdgcn_mfma_f32_32x32x16_bf16(af[r][0], wf[c][0], d, 0, 0, 0);
                d = __builtin_amdgcn_mfma_f32_32x32x16_bf16(af[r][0], wf[c][1], d, 0, 0, 0);
                d = __builtin_amdgcn_mfma_f32_32x32x16_bf16(af[r][1], wf[c][0], d, 0, 0, 0);
                d = __builtin_amdgcn_mfma_f32_32x32x16_bf16(af[r][0], wf[c][2], d, 0, 0, 0);
                d = __builtin_amdgcn_mfma_f32_32x32x16_bf16(af[r][2], wf[c][0], d, 0, 0, 0);
                d = __builtin_amdgcn_mfma_f32_32x32x16_bf16(af[r][1], wf[c][1], d, 0, 0, 0);
                acc[r][c] = d;
            }
        __syncthreads();                  // reads done before next swrite
    }
    int rowBase = blockIdx.y * 128;
    long colBase = (long)blockIdx.x * 128;
    #pragma unroll
    for (int r = 0; r < 2; ++r) {
        int rb = rowBase + wr * 64 + r * 32 + 4 * l5;
        #pragma unroll
        for (int c = 0; c < 2; ++c) {
            long cb = colBase + wc * 64 + c * 32 + l31;
            float bv = bias[cb];
            #pragma unroll
            for (int i = 0; i < 16; ++i) {
                int rr = rb + (i & 3) + 8 * (i >> 2);
                if (rr < ROWS) C[(long)rr * ENDIM + cb] = acc[r][c][i] + bv;
            }
        }
    }
}

// ------------------------------------------------------------------
// SMALL fp32 GEMM: one WAVE per 32x32 tile, 4x4/thread, double-
// buffered LDS. gridDim.z selects two independent sets (Wx+Wz, Df+Db).
// SP = correctly-rounded softplus epilogue. k-ascending FMA order
// (Delta path must stay bit-exact: P-trajectory depends on it).
// ------------------------------------------------------------------
#define SBK 16
template<bool SP, bool HASB2, bool HASRES>
__global__ __launch_bounds__(64) void gemm_s(const float* __restrict__ A0,
                                             const float* __restrict__ W0,
                                             const float* __restrict__ b10,
                                             const float* __restrict__ b20,
                                             const float* __restrict__ r0,
                                             float* __restrict__ C0,
                                             const float* __restrict__ A1,
                                             const float* __restrict__ W1,
                                             const float* __restrict__ b11,
                                             const float* __restrict__ b21,
                                             const float* __restrict__ r1,
                                             float* __restrict__ C1,
                                             int M, int N, int K) {
    const float* A  = blockIdx.z ? A1  : A0;
    const float* W  = blockIdx.z ? W1  : W0;
    const float* bp = blockIdx.z ? b11 : b10;
    const float* b2 = blockIdx.z ? b21 : b20;
    const float* rp = blockIdx.z ? r1  : r0;
    float*       C  = blockIdx.z ? C1  : C0;
    __shared__ float As[2][SBK][36];
    __shared__ float Wsh[2][SBK][36];
    int t = threadIdx.x;            // 0..63
    int tx = t & 7, ty = t >> 3;
    int rowBase = blockIdx.y * 32;
    long colBase = (long)blockIdx.x * 32;
    int rA = t >> 2, kqA = (t & 3) << 2;
    int kW = t >> 3, nqW = (t & 7) << 2;
    float acc[4][4] = {};
    int r0i = rowBase + rA, r1i = r0i + 16;

    auto loadA = [&](int k0, float4& a0, float4& a1) {
        a0 = make_float4(0.f,0.f,0.f,0.f); a1 = a0;
        if (r0i < M) a0 = *(const float4*)&A[(long)r0i * K + k0 + kqA];
        if (r1i < M) a1 = *(const float4*)&A[(long)r1i * K + k0 + kqA];
    };
    auto stage = [&](int buf, float4 a0, float4 a1, float4 w0, float4 w1) {
        As[buf][kqA + 0][rA] = a0.x; As[buf][kqA + 1][rA] = a0.y;
        As[buf][kqA + 2][rA] = a0.z; As[buf][kqA + 3][rA] = a0.w;
        As[buf][kqA + 0][rA + 16] = a1.x; As[buf][kqA + 1][rA + 16] = a1.y;
        As[buf][kqA + 2][rA + 16] = a1.z; As[buf][kqA + 3][rA + 16] = a1.w;
        *(float4*)&Wsh[buf][kW][nqW]     = w0;
        *(float4*)&Wsh[buf][kW + 8][nqW] = w1;
    };
    auto compute = [&](int buf) {
        #pragma unroll
        for (int kk = 0; kk < SBK; ++kk) {
            float4 av = *(const float4*)&As[buf][kk][ty << 2];
            float4 wv = *(const float4*)&Wsh[buf][kk][tx << 2];
            float ar[4] = {av.x, av.y, av.z, av.w};
            float wr[4] = {wv.x, wv.y, wv.z, wv.w};
            #pragma unroll
            for (int i = 0; i < 4; ++i)
                #pragma unroll
                for (int j = 0; j < 4; ++j) acc[i][j] += ar[i] * wr[j];
        }
    };

    {
        float4 a0, a1;
        loadA(0, a0, a1);
        float4 w0 = *(const float4*)&W[(long)kW * N + colBase + nqW];
        float4 w1 = *(const float4*)&W[(long)(kW + 8) * N + colBase + nqW];
        stage(0, a0, a1, w0, w1);
    }
    __syncthreads();
    int cur = 0;
    int nt = K / SBK;
    for (int kt = 1; kt < nt; ++kt) {
        int k0 = kt * SBK;
        float4 a0, a1;
        loadA(k0, a0, a1);
        float4 w0 = *(const float4*)&W[(long)(k0 + kW) * N + colBase + nqW];
        float4 w1 = *(const float4*)&W[(long)(k0 + kW + 8) * N + colBase + nqW];
        compute(cur);
        stage(cur ^ 1, a0, a1, w0, w1);
        __syncthreads();
        cur ^= 1;
    }
    compute(cur);

    #pragma unroll
    for (int i = 0; i < 4; ++i) {
        int r = rowBase + (ty << 2) + i;
        if (r >= M) break;
        long cb = colBase + (tx << 2);
        float vv[4];
        #pragma unroll
        for (int j = 0; j < 4; ++j) {
            float v = acc[i][j] + bp[cb + j];
            if (HASB2) v += b2[cb + j];
            if (SP) {  // correctly-rounded fp32 softplus via fp64
                double vd = (double)v;
                v = (float)(log1p(exp(-fabs(vd))) + fmax(vd, 0.0));
            }
            if (HASRES) v += rp[(long)r * N + cb + j];
            vv[j] = v;
        }
        float4 o; o.x = vv[0]; o.y = vv[1]; o.z = vv[2]; o.w = vv[3];
        *(float4*)&C[(long)r * N + cb] = o;
    }
}

// ------------------------------------------------------------------
// fused depthwise conv (fwd + bwd) + SiLU
// ------------------------------------------------------------------
__global__ __launch_bounds__(256) void dwconv_k(const float* __restrict__ xp,
                                                const float* __restrict__ wf,
                                                const float* __restrict__ bf,
                                                const float* __restrict__ wb,
                                                const float* __restrict__ bb,
                                                float* __restrict__ xf,
                                                float* __restrict__ xb) {
    int idx = blockIdx.x * 256 + threadIdx.x;
    if (idx >= ROWS * EDIM) return;
    int e = idx % EDIM;
    int bm = idx / EDIM;
    int m = bm % MSEQ, b = bm / MSEQ;
    const float* base = xp + (long)b * MSEQ * EDIM + e;
    float xm1 = (m > 0)        ? base[(m - 1) * EDIM] : 0.f;
    float x0  =                  base[m * EDIM];
    float xp1 = (m < MSEQ - 1) ? base[(m + 1) * EDIM] : 0.f;
    float f = wf[e * 3 + 0] * xm1 + wf[e * 3 + 1] * x0 + wf[e * 3 + 2] * xp1 + bf[e];
    float r = wb[e * 3 + 0] * xp1 + wb[e * 3 + 1] * x0 + wb[e * 3 + 2] * xm1 + bb[e];
    xf[idx] = silu_f(f);
    xb[idx] = silu_f(r);
}

// ------------------------------------------------------------------
// SSM recurrence, PHASE-PARALLEL, bit-exact fp32 chains; CR fp64
// transcendentals. One block per (b,e). ycomb!=nullptr fuses combine.
// ------------------------------------------------------------------
__global__ __launch_bounds__(256) void ssm_scan_k(const float* __restrict__ Bm,
                                                  const float* __restrict__ Cm,
                                                  const float* __restrict__ Dlt,
                                                  const float* __restrict__ xs,
                                                  const float* __restrict__ Apar,
                                                  float* __restrict__ y,
                                                  const float* __restrict__ yother,
                                                  const float* __restrict__ zg,
                                                  float* __restrict__ ycomb) {
#pragma clang fp contract(off)
    __shared__ float lgP[MSEQ][17];
    __shared__ float trm[MSEQ][17];
    __shared__ signed char sgn[MSEQ][17];
    int be = blockIdx.x;
    int b = be / EDIM, e = be - b * EDIM;
    int t = threadIdx.x;
    int n0 = t & 15;
    float Ap = Apar[e * NSTATE + n0];
    const long dxBase = (long)b * MSEQ * EDIM + e;
    const long bcBase = (long)b * MSEQ * ENDIM + e * NSTATE;

    for (int idx = t; idx < MSEQ * NSTATE; idx += 256) {
        int m = idx >> 4;
        float delta = Dlt[dxBase + (long)m * EDIM];
        float A = delta * Ap;
        float sa = (A > 0.f) ? 1.f : ((A < 0.f) ? -1.f : 0.f);
        float absA = fmaxf(fabsf(A), 1e-6f);
        lgP[m][n0] = (float)log((double)absA);
        sgn[m][n0] = (signed char)sa;
    }
    __syncthreads();
    if (t < NSTATE) {
        float cl = 0.f, cs = 1.f;
        for (int m = 0; m < MSEQ; ++m) {
            float sa = (float)sgn[m][t];
            cs = cs * sa;
            cl = cl + lgP[m][t];
            lgP[m][t] = cl;
            sgn[m][t] = (signed char)cs;
        }
    }
    __syncthreads();
    for (int idx = t; idx < MSEQ * NSTATE; idx += 256) {
        int m = idx >> 4;
        float cl = lgP[m][n0];
        float cs = (float)sgn[m][n0];
        float ex = (float)exp((double)cl);
        float P = cs * ex;
        float tt = P + 1e-6f;
        float invP = 1.0f / tt;
        float delta = Dlt[dxBase + (long)m * EDIM];
        float xv = xs[dxBase + (long)m * EDIM];
        float Bv = Bm[bcBase + (long)m * ENDIM + n0];
        float Bfull = delta * Bv;
        float t1 = invP * Bfull;
        float t2 = t1 * xv;
        trm[m][n0] = t2;
        lgP[m][n0] = P;
    }
    __syncthreads();
    if (t < NSTATE) {
        float S = 0.f;
        for (int m = 0; m < MSEQ; ++m) {
            S = S + trm[m][t];
            float h = lgP[m][t] * S;
            trm[m][t] = h;
        }
    }
    __syncthreads();
    for (int m = t; m < MSEQ; m += 256) {
        const float* cp = &Cm[bcBase + (long)m * ENDIM];
        float a[16];
        #pragma unroll
        for (int n = 0; n < 16; ++n) a[n] = trm[m][n] * cp[n];
        float b0 = a[0] + a[8],  b1 = a[1] + a[9];
        float b2v = a[2] + a[10], b3 = a[3] + a[11];
        float b4 = a[4] + a[12], b5 = a[5] + a[13];
        float b6 = a[6] + a[14], b7 = a[7] + a[15];
        float c0 = b0 + b1, c2 = b2v + b3, c4 = b4 + b5, c6 = b6 + b7;
        float d0 = c0 + c2, d4 = c4 + c6;
        float val = d0 + d4;
        long o = dxBase + (long)m * EDIM;
        if (ycomb) ycomb[o] = (yother[o] + val) * silu_f(zg[o]);
        else       y[o] = val;
    }
}

extern "C" void kernel_launch(void* const* d_in, const int* in_sizes, int n_in,
                              void* d_out, int out_size, void* d_ws, size_t ws_size,
                              hipStream_t stream) {
    const float* img     = (const float*)d_in[0];
    const float* patch_w = (const float*)d_in[1];
    const float* patch_b = (const float*)d_in[2];
    const float* cls     = (const float*)d_in[3];
    const float* pos     = (const float*)d_in[4];
    const float* ln_g    = (const float*)d_in[5];
    const float* ln_b    = (const float*)d_in[6];
    const float* Wx  = (const float*)d_in[7];  const float* bx  = (const float*)d_in[8];
    const float* Wz  = (const float*)d_in[9];  const float* bz  = (const float*)d_in[10];
    const float* cwf = (const float*)d_in[11]; const float* cbf = (const float*)d_in[12];
    const float* cwb = (const float*)d_in[13]; const float* cbb = (const float*)d_in[14];
    const float* WBf = (const float*)d_in[15]; const float* bBf = (const float*)d_in[16];
    const float* WCf = (const float*)d_in[17]; const float* bCf = (const float*)d_in[18];
    const float* WDf = (const float*)d_in[19]; const float* bDf = (const float*)d_in[20];
    const float* Af  = (const float*)d_in[21]; const float* dbf = (const float*)d_in[22];
    const float* WBb = (const float*)d_in[23]; const float* bBb = (const float*)d_in[24];
    const float* WCb = (const float*)d_in[25]; const float* bCb = (const float*)d_in[26];
    const float* WDb = (const float*)d_in[27]; const float* bDb = (const float*)d_in[28];
    const float* Ab  = (const float*)d_in[29]; const float* dbb = (const float*)d_in[30];
    const float* Wout= (const float*)d_in[31]; const float* bout= (const float*)d_in[32];
    const float* ng  = (const float*)d_in[33]; const float* nb  = (const float*)d_in[34];

    float* ws = (float*)d_ws;
    float* xA   = ws;
    float* xB   = xA  + (size_t)ROWS * DDIM;
    float* xn   = xB  + (size_t)ROWS * DDIM;
    float* xp   = xn  + (size_t)ROWS * DDIM;
    float* zb   = xp  + (size_t)ROWS * EDIM;
    float* xfb  = zb  + (size_t)ROWS * EDIM;
    float* xbb  = xfb + (size_t)ROWS * EDIM;
    float* yfb  = xbb + (size_t)ROWS * EDIM;
    float* ybb  = yfb + (size_t)ROWS * EDIM;
    float* ycb  = ybb + (size_t)ROWS * EDIM;
    float* dlt  = ycb + (size_t)ROWS * EDIM;
    float* dlt2 = dlt + (size_t)ROWS * EDIM;
    float* Bmb  = dlt2 + (size_t)ROWS * EDIM;         // ROWS*ENDIM
    float* Cmb  = Bmb + (size_t)ROWS * ENDIM;
    u16*   Af3  = (u16*)(Cmb + (size_t)ROWS * ENDIM); // [3][MFRAGS][KBLKS][FRAG]
    u16*   Ab3  = Af3 + 3L * MFRAGS * KBLKS * FRAG;
    u16*   Wt4  = Ab3 + 3L * MFRAGS * KBLKS * FRAG;   // [4][3][NFRAGS][KBLKS][FRAG]
    // patchify scratch aliases the (not-yet-needed) B buffer
    float* patches = Bmb;                             // PROWS*PATCH_K
    float* xemb    = Bmb + (size_t)PROWS * PATCH_K;   // PROWS*DDIM

    const long WtSz = 3L * NFRAGS * KBLKS * FRAG;     // u16 per converted matrix

    // --- patch embedding ---
    patchify_k<<<(PROWS * PATCH_K + 255) / 256, 256, 0, stream>>>(img, patches);
    {   // 1568x192x768 GEMM
        dim3 g(DDIM / 32, (PROWS + 31) / 32, 1);
        gemm_s<false, false, false><<<g, 64, 0, stream>>>(
            patches, patch_w, patch_b, nullptr, nullptr, xemb,
            patches, patch_w, patch_b, nullptr, nullptr, xemb,
            PROWS, DDIM, PATCH_K);
    }
    assemble_k<<<(ROWS * DDIM + 255) / 256, 256, 0, stream>>>(xemb, cls, pos, xA);

    float* cur = xA; float* nxt = xB;
    for (int i = 0; i < LLAYERS; ++i) {
        layernorm_k<<<(ROWS + 3) / 4, 256, 0, stream>>>(cur, ln_g + i * DDIM, ln_b + i * DDIM, xn, ROWS);
        {   // Wx + Wz fused (shared A=xn)
            dim3 g(EDIM / 32, (ROWS + 31) / 32, 2);
            gemm_s<false, false, false><<<g, 64, 0, stream>>>(
                xn, Wx + (size_t)i * DDIM * EDIM, bx + i * EDIM, nullptr, nullptr, xp,
                xn, Wz + (size_t)i * DDIM * EDIM, bz + i * EDIM, nullptr, nullptr, zb,
                ROWS, EDIM, DDIM);
        }
        dwconv_k<<<(ROWS * EDIM + 255) / 256, 256, 0, stream>>>(xp, cwf + i * EDIM * 3, cbf + i * EDIM,
                                                                cwb + i * EDIM * 3, cbb + i * EDIM, xfb, xbb);
        convA_k<<<(MFRAGS * KBLKS * 64 + 255) / 256, 256, 0, stream>>>(xfb, xbb, Af3, Ab3);
        {   // Df + Db fused (CR softplus epilogue) — fp32 path, P stays bit-exact
            dim3 g(EDIM / 32, (ROWS + 31) / 32, 2);
            gemm_s<true, true, false><<<g, 64, 0, stream>>>(
                xfb, WDf + (size_t)i * EDIM * EDIM, bDf + i * EDIM, dbf + i * EDIM, nullptr, dlt,
                xbb, WDb + (size_t)i * EDIM * EDIM, bDb + i * EDIM, dbb + i * EDIM, nullptr, dlt2,
                ROWS, EDIM, EDIM);
        }
        {   // convert the 4 big weight matrices -> fragment-ordered bf16x3 planes
            dim3 g(ENDIM / 64, EDIM / 64, 4);
            convWt_k<<<g, 256, 0, stream>>>(
                WBf + (size_t)i * EDIM * ENDIM, WCf + (size_t)i * EDIM * ENDIM,
                WBb + (size_t)i * EDIM * ENDIM, WCb + (size_t)i * EDIM * ENDIM, Wt4);
        }
        {   // Bf + Cf via MFMA (shared A planes); 128x128 tiles
            dim3 g(ENDIM / 128, AP_ROWS / 128, 2);
            gemm_mfma<<<g, 256, 0, stream>>>(
                Af3,
                Wt4 + 0 * WtSz, bBf + i * ENDIM, Bmb,
                Wt4 + 1 * WtSz, bCf + i * ENDIM, Cmb);
        }
        ssm_scan_k<<<BATCH * EDIM, 256, 0, stream>>>(Bmb, Cmb, dlt, xfb, Af + i * EDIM * NSTATE,
                                                     yfb, nullptr, nullptr, nullptr);
        {   // Bb + Cb via MFMA
            dim3 g(ENDIM / 128, AP_ROWS / 128, 2);
            gemm_mfma<<<g, 256, 0, stream>>>(
                Ab3,
                Wt4 + 2 * WtSz, bBb + i * ENDIM, Bmb,
                Wt4 + 3 * WtSz, bCb + i * ENDIM, Cmb);
        }
        // bwd scan with FUSED combine: ycb = (yfb + y_b) * silu(zb)
        ssm_scan_k<<<BATCH * EDIM, 256, 0, stream>>>(Bmb, Cmb, dlt2, xbb, Ab + i * EDIM * NSTATE,
                                                     ybb, yfb, zb, ycb);
        {   // Wout with residual
            dim3 g(DDIM / 32, (ROWS + 31) / 32, 1);
            gemm_s<false, false, true><<<g, 64, 0, stream>>>(
                ycb, Wout + (size_t)i * EDIM * DDIM, bout + i * DDIM, nullptr, cur, nxt,
                ycb, Wout + (size_t)i * EDIM * DDIM, bout + i * DDIM, nullptr, cur, nxt,
                ROWS, DDIM, EDIM);
        }
        float* t = cur; cur = nxt; nxt = t;
    }
    layernorm_k<<<(ROWS + 3) / 4, 256, 0, stream>>>(cur, ng, nb, (float*)d_out, ROWS);
}